// Round 8
// baseline (119.681 us; speedup 1.0000x reference)
//
#include <hip/hip_runtime.h>

typedef float v2f __attribute__((ext_vector_type(2)));

// ---- problem ----
// x:[4,16,8,64,64] f32, w_q/w_k/w_v:[64,8] f32, w_p:[2] f32
// out:[4,16,64,64,64] f32
// Attention batch B = bb*64 + o: q-side channel i (all 16) row o;
// k/v-side channel o>>2, w_k/w_v rows (o&3)*16+j; uk += 2*pe; scale 0.125
// folded into w_q (plus log2e when exp2 available); residual = mean over m;
// single-pass softmax (|logit| << 88): out = (sum_j e_j*uv_j)/(sum_j e_j).
//
// R18: block-granularity halving. Evidence: block-size gradient 512thr=58.5,
// 256thr=53 (smaller better); R11's 16-wave/4-block config = 65. Theory:
// the stall term is barrier-group size + too few independently-phased
// blocks/CU to overlap the VMEM prologue / LDS+VALU stages. Block = one
// row-pair x 32-col half (128 thr, 2 waves): LDS 10240 B -> 16 blocks/CU,
// 32 waves/CU static at VGPR<=64, 2-wave barrier groups. Stage 2 = two
// j-passes (j=jg, jg+8) re-reading s_xk so live weights stay 16 scalars
// (register peak ~R13's 56; the <=64 cliff is the hard constraint).
// Per-thread pipe counts ~= R13 (VMEM +4 weight loads, LDS/VALU same).
// RULE (2x confirmed): launch_bounds min-waves must stay <=4 (8 -> spills).

#if __has_builtin(__builtin_amdgcn_exp2f)
  #define EXP_FN(x) __builtin_amdgcn_exp2f(x)
  #define QSCALE 0.18033688011112043f   // 0.125 * log2(e)
#else
  #define EXP_FN(x) __expf(x)
  #define QSCALE 0.125f
#endif
#if __has_builtin(__builtin_amdgcn_rcpf)
  #define RCP_FN(x) __builtin_amdgcn_rcpf(x)
#else
  #define RCP_FN(x) (1.0f/(x))
#endif

__global__ __launch_bounds__(128, 4) void adapt_attn(
    const float* __restrict__ x,  const float* __restrict__ wq,
    const float* __restrict__ wk, const float* __restrict__ wv,
    const float* __restrict__ wp, float* __restrict__ out)
{
    __shared__ __align__(16) v2f s_xk[8][2][16];   // 2 KB [m][row][p]
    __shared__ float4 s_uk[16][16];                // 4 KB [j][p]
    __shared__ float4 s_uv[16][16];                // 4 KB  -> 10240 total

    const int tid = threadIdx.x;          // 0..127
    const int bid = blockIdx.x;           // ((bb*64+o)*64)+u ; 16384 blocks
    const int u   = bid & 63;             // row-pair (u>>1), col-half (u&1)
    const int o   = (bid >> 6) & 63;
    const int bb  = bid >> 12;
    const int r = o & 3, qch = o >> 2;
    const int y0  = (u >> 1) << 1;        // top row of the pair
    const int hv  = (u & 1) << 4;         // column-half offset, v2f units

    const v2f*    __restrict__ x2 = (const v2f*)x;    // v2f strides: m 2048, row 32
    const float4* __restrict__ x4 = (const float4*)x; // f4 strides: m 1024, row 16

    // ---- A: issue k/v staging load (1 float4 per thread = 2 KB total) ----
    float4 s1;
    {
        const int f = tid & 7, row = (tid >> 3) & 1, m = tid >> 4;
        s1 = x4[((bb * 16 + qch) * 8 + m) * 1024 + (y0 + row) * 16 + (hv >> 1) + f];
    }

    // ---- pe terms for stage 2 (independent of loads) ----
    const int p2 = tid & 15, jg = tid >> 4;          // jg 0..7
    const float wp0 = wp[0], wp1 = wp[1];
    const float step = 2.0f / 63.0f;
    const int   wwp  = hv + p2;                      // global v2f column
    const float lx0 = -1.0f + step * (float)(wwp << 1);
    const float lx1 = lx0 + step;
    const float ly0 = -1.0f + step * (float)y0;
    const float ly1 = ly0 + step;
    const v2f pea = { 2.0f * (wp0 * lx0 + wp1 * ly0), 2.0f * (wp0 * lx1 + wp1 * ly0) };
    const v2f peb = { 2.0f * (wp0 * lx0 + wp1 * ly1), 2.0f * (wp0 * lx1 + wp1 * ly1) };

    // ---- D: staging store ----
    {
        const int f = tid & 7, row = (tid >> 3) & 1, m = tid >> 4;
        *(float4*)&s_xk[m][row][f * 2] = s1;
    }
    __syncthreads();

    // ---- stage 2: two j-passes (j = jg, jg+8); 16 live weight scalars ----
    #pragma unroll
    for (int pass = 0; pass < 2; pass++) {
        const int j = jg + (pass << 3);
        float wkj[8], wvj[8];
        {
            const float4* wk4 = (const float4*)wk;
            const float4* wv4 = (const float4*)wv;
            const int rb = (r * 16 + j) * 2;
            *(float4*)&wkj[0] = wk4[rb];   *(float4*)&wkj[4] = wk4[rb + 1];
            *(float4*)&wvj[0] = wv4[rb];   *(float4*)&wvj[4] = wv4[rb + 1];
        }
        v2f ka = pea, kb = peb, va = {0.f, 0.f}, vb = {0.f, 0.f};
        #pragma unroll
        for (int m = 0; m < 8; m++) {
            const v2f xa = s_xk[m][0][p2];
            const v2f xb = s_xk[m][1][p2];
            ka += xa * wkj[m]; kb += xb * wkj[m];
            va += xa * wvj[m]; vb += xb * wvj[m];
        }
        s_uk[j][p2] = make_float4(ka.x, ka.y, kb.x, kb.y);
        s_uv[j][p2] = make_float4(va.x, va.y, vb.x, vb.y);
    }

    // ---- C: q loads + q-conv + residual (issued before barrier 2 so the
    //         load burst overlaps the rendezvous; consumed after) ----
    const int p3 = tid & 15, ig = tid >> 4;          // i-pair 2ig, 2ig+1
    const int sp = y0 * 32 + hv + p3;                // v2f offset in 64x64 plane

    float wqr[8];
    #pragma unroll
    for (int m = 0; m < 8; m++)
        wqr[m] = QSCALE * wq[(o << 3) + m];          // uniform scalar loads

    v2f qa0[8], qb0[8], qa1[8], qb1[8];
    {
        const int bq0 = (bb * 16 + ig * 2) * 16384 + sp;
        const int bq1 = bq0 + 16384;
        #pragma unroll
        for (int m = 0; m < 8; m++) {                // lanes 0-15 coalesced 128B
            qa0[m] = x2[bq0 + m * 2048];
            qb0[m] = x2[bq0 + m * 2048 + 32];
            qa1[m] = x2[bq1 + m * 2048];
            qb1[m] = x2[bq1 + m * 2048 + 32];
        }
    }

    v2f uqa0 = {0.f,0.f}, uqb0 = {0.f,0.f}, rsa0 = {0.f,0.f}, rsb0 = {0.f,0.f};
    v2f uqa1 = {0.f,0.f}, uqb1 = {0.f,0.f}, rsa1 = {0.f,0.f}, rsb1 = {0.f,0.f};
    #pragma unroll
    for (int m = 0; m < 8; m++) {
        uqa0 += qa0[m] * wqr[m];          // wq pre-scaled (incl. log2e)
        uqb0 += qb0[m] * wqr[m];
        rsa0 += qa0[m];
        rsb0 += qb0[m];
        uqa1 += qa1[m] * wqr[m];
        uqb1 += qb1[m] * wqr[m];
        rsa1 += qa1[m];
        rsb1 += qb1[m];
    }
    __syncthreads();     // s_uk/s_uv ready (2-wave rendezvous)

    // ---- stage 3: fused att + softmax + AV ----
    {
        v2f oa0 = {0.f, 0.f}, ob0 = {0.f, 0.f};
        v2f oa1 = {0.f, 0.f}, ob1 = {0.f, 0.f};
        float sum0 = 0.f, sum1 = 0.f;

        #pragma unroll
        for (int j = 0; j < 16; j++) {
            const float4 k4 = s_uk[j][p3];    // 4-dup broadcast: free
            const float4 v4 = s_uv[j][p3];
            const v2f ka = {k4.x, k4.y}, kb = {k4.z, k4.w};
            const v2f va = {v4.x, v4.y}, vb = {v4.z, v4.w};

            v2f t0 = uqa0 * ka;
            t0 += uqb0 * kb;
            const float e0 = EXP_FN(t0.x + t0.y);
            sum0 += e0;
            oa0 += va * e0;
            ob0 += vb * e0;

            v2f t1 = uqa1 * ka;
            t1 += uqb1 * kb;
            const float e1 = EXP_FN(t1.x + t1.y);
            sum1 += e1;
            oa1 += va * e1;
            ob1 += vb * e1;
        }

        v2f* __restrict__ out2 = (v2f*)out;
        {
            const int i = ig * 2;
            const float rcp = RCP_FN(sum0);
            const v2f outa = oa0 * rcp + rsa0 * 0.125f;   // residual = mean/m
            const v2f outb = ob0 * rcp + rsb0 * 0.125f;
            const int obi = ((bb * 16 + i) * 64 + o) * 2048 + sp;
            out2[obi]      = outa;    // row y0
            out2[obi + 32] = outb;    // row y0+1
        }
        {
            const int i = ig * 2 + 1;
            const float rcp = RCP_FN(sum1);
            const v2f outa = oa1 * rcp + rsa1 * 0.125f;
            const v2f outb = ob1 * rcp + rsb1 * 0.125f;
            const int obi = ((bb * 16 + i) * 64 + o) * 2048 + sp;
            out2[obi]      = outa;
            out2[obi + 32] = outb;
        }
    }
}

extern "C" void kernel_launch(void* const* d_in, const int* in_sizes, int n_in,
                              void* d_out, int out_size, void* d_ws, size_t ws_size,
                              hipStream_t stream) {
    const float* x  = (const float*)d_in[0];
    const float* wq = (const float*)d_in[1];
    const float* wk = (const float*)d_in[2];
    const float* wv = (const float*)d_in[3];
    const float* wp = (const float*)d_in[4];
    float* out = (float*)d_out;
    // 4 bb * 64 o * 64 (row-pair x col-half) = 16384 blocks of 128 threads
    adapt_attn<<<dim3(16384), dim3(128), 0, stream>>>(x, wq, wk, wv, wp, out);
}

// Round 9
// 119.317 us; speedup vs baseline: 1.0031x; 1.0031x over previous
//
#include <hip/hip_runtime.h>

typedef float v2f __attribute__((ext_vector_type(2)));

// ---- problem ----
// x:[4,16,8,64,64] f32, w_q/w_k/w_v:[64,8] f32, w_p:[2] f32
// out:[4,16,64,64,64] f32
// Attention batch B = bb*64 + o: q-side channel i (all 16) row o;
// k/v-side channel o>>2, w_k/w_v rows (o&3)*16+j; uk += 2*pe; scale 0.125
// folded into w_q (plus log2e); residual = mean over m; single-pass
// softmax: out = (sum_j e_j*uv_j)/(sum_j e_j).
//
// R19: software-pipelined 2-item blocks. Evidence: across R10-R18, dur is
// pinned 52-58 us and dur*VALUBusy == 26 us while occupancy (25-56%), block
// size, LDS/VMEM mix all varied -> co-resident blocks run the SAME phase at
// the same time (lockstep through identical code+barriers), so the CU
// ping-pongs VMEM-storm / VALU-storm / LDS-storm and dur == sum of phases.
// Fix: overlap pipes WITHIN the stream. Each block = 2 R13-items, double-
// buffered LDS; window W1 = stage2(item0) [LDS+VALU] + q-loads(item1)
// [VMEM]; W2 = stage3(item0) [LDS+VALU+exp+stores] + stage2(item1).
// 3 barriers / 2 items (was 4). LDS 40960 -> 4 blocks/CU. (256,4) -> VGPR
// cap 128; q-loads in 2-m sub-bursts to hold peak ~110.
// RULE (2x): launch_bounds min-waves must stay <=4 (8 -> catastrophic spill).

#if __has_builtin(__builtin_amdgcn_exp2f)
  #define EXP_FN(x) __builtin_amdgcn_exp2f(x)
  #define QSCALE 0.18033688011112043f   // 0.125 * log2(e)
#else
  #define EXP_FN(x) __expf(x)
  #define QSCALE 0.125f
#endif
#if __has_builtin(__builtin_amdgcn_rcpf)
  #define RCP_FN(x) __builtin_amdgcn_rcpf(x)
#else
  #define RCP_FN(x) (1.0f/(x))
#endif

__global__ __launch_bounds__(256, 4) void adapt_attn(
    const float* __restrict__ x,  const float* __restrict__ wq,
    const float* __restrict__ wk, const float* __restrict__ wv,
    const float* __restrict__ wp, float* __restrict__ out)
{
    __shared__ __align__(16) v2f s_xk[2][2][8][2][16]; // 8 KB  [pb][t][m][row][p]
    __shared__ float4 s_uk[2][2][16][16];              // 16 KB [pb][t][j][p]
    __shared__ float4 s_uv[2][2][16][16];              // 16 KB  -> 40960 total

    const int tid = threadIdx.x;          // 0..255
    const int bid = blockIdx.x;           // ((bb*64+o)*16)+u ; 4096 blocks
    const int u   = bid & 15;             // items: tile-pairs 2u, 2u+1
    const int o   = (bid >> 4) & 63;
    const int bb  = bid >> 10;
    const int r = o & 3, qch = o >> 2;

    const v2f*    __restrict__ x2 = (const v2f*)x;    // v2f strides: m 2048, row 32
    const float4* __restrict__ x4 = (const float4*)x; // f4 strides: m 1024, row 16

    // thread mappings (shared by both items)
    const int sf = tid & 7, srow = (tid >> 3) & 1, sm = (tid >> 4) & 7, st = tid >> 7;
    const int p2 = tid & 15, j2 = (tid >> 4) & 15;
    const int p3 = tid & 15, ig = (tid >> 4) & 7, t3 = tid >> 7;
    const float step = 2.0f / 63.0f;

    // ---- W0: all VMEM issued up front ----
    const int kvbase = ((bb * 16 + qch) * 8 + sm) * 1024 + srow * 16 + sf;
    float4 s1_0, s1_1;
    {   const int tile0 = (2 * u + 0) * 2 + st;
        s1_0 = x4[kvbase + ((tile0 >> 1) << 1) * 16 + (tile0 & 1) * 8];
        const int tile1 = (2 * u + 1) * 2 + st;
        s1_1 = x4[kvbase + ((tile1 >> 1) << 1) * 16 + (tile1 & 1) * 8];
    }
    float wkj[8], wvj[8];
    {   const float4* wk4 = (const float4*)wk;
        const float4* wv4 = (const float4*)wv;
        const int rb = (r * 16 + j2) * 2;
        *(float4*)&wkj[0] = wk4[rb];   *(float4*)&wkj[4] = wk4[rb + 1];
        *(float4*)&wvj[0] = wv4[rb];   *(float4*)&wvj[4] = wv4[rb + 1];
    }
    float wqr[8];
    #pragma unroll
    for (int m = 0; m < 8; m++)
        wqr[m] = QSCALE * wq[(o << 3) + m];          // uniform scalar loads
    const float wp0 = wp[0], wp1 = wp[1];

    // q-conv for one item: loads in 2-m sub-bursts (16 VGPR transient)
    auto qconv = [&](int tgi, v2f& uqa0, v2f& uqb0, v2f& uqa1, v2f& uqb1,
                     v2f& rsa0, v2f& rsb0, v2f& rsa1, v2f& rsb1) -> int {
        const int tile3 = tgi * 2 + t3;
        const int y03 = (tile3 >> 1) << 1, ww03 = (tile3 & 1) << 4;
        const int sp = y03 * 32 + ww03 + p3;
        const int bq0 = (bb * 16 + ig * 2) * 16384 + sp;
        const int bq1 = bq0 + 16384;
        #pragma unroll
        for (int mh = 0; mh < 4; mh++) {
            const int m0 = 2 * mh, m1 = 2 * mh + 1;
            const v2f a0  = x2[bq0 + m0 * 2048],      a0b = x2[bq0 + m0 * 2048 + 32];
            const v2f a1  = x2[bq0 + m1 * 2048],      a1b = x2[bq0 + m1 * 2048 + 32];
            const v2f c0  = x2[bq1 + m0 * 2048],      c0b = x2[bq1 + m0 * 2048 + 32];
            const v2f c1  = x2[bq1 + m1 * 2048],      c1b = x2[bq1 + m1 * 2048 + 32];
            uqa0 += a0 * wqr[m0];  uqa0 += a1 * wqr[m1];
            uqb0 += a0b * wqr[m0]; uqb0 += a1b * wqr[m1];
            uqa1 += c0 * wqr[m0];  uqa1 += c1 * wqr[m1];
            uqb1 += c0b * wqr[m0]; uqb1 += c1b * wqr[m1];
            rsa0 += a0;  rsa0 += a1;   rsb0 += a0b; rsb0 += a1b;
            rsa1 += c0;  rsa1 += c1;   rsb1 += c0b; rsb1 += c1b;
        }
        return sp;
    };

    auto stage2 = [&](int tgi, int pb) {
        #pragma unroll
        for (int t = 0; t < 2; t++) {
            const int tile = tgi * 2 + t;
            const int y0 = (tile >> 1) << 1, ww0 = (tile & 1) << 4;
            const int wwp = ww0 + p2;
            const float lx0 = -1.0f + step * (float)(wwp << 1);
            const float lx1 = lx0 + step;
            const float ly0 = -1.0f + step * (float)y0;
            const float ly1 = ly0 + step;
            v2f ka = { 2.0f * (wp0 * lx0 + wp1 * ly0), 2.0f * (wp0 * lx1 + wp1 * ly0) };
            v2f kb = { 2.0f * (wp0 * lx0 + wp1 * ly1), 2.0f * (wp0 * lx1 + wp1 * ly1) };
            v2f va = {0.f, 0.f}, vb = {0.f, 0.f};
            #pragma unroll
            for (int m = 0; m < 8; m++) {
                const v2f xa = s_xk[pb][t][m][0][p2];
                const v2f xb = s_xk[pb][t][m][1][p2];
                ka += xa * wkj[m]; kb += xb * wkj[m];
                va += xa * wvj[m]; vb += xb * wvj[m];
            }
            s_uk[pb][t][j2][p2] = make_float4(ka.x, ka.y, kb.x, kb.y);
            s_uv[pb][t][j2][p2] = make_float4(va.x, va.y, vb.x, vb.y);
        }
    };

    auto stage3 = [&](int pb, int sp,
                      v2f uqa0, v2f uqb0, v2f uqa1, v2f uqb1,
                      v2f rsa0, v2f rsb0, v2f rsa1, v2f rsb1) {
        v2f oa0 = {0.f, 0.f}, ob0 = {0.f, 0.f};
        v2f oa1 = {0.f, 0.f}, ob1 = {0.f, 0.f};
        float sum0 = 0.f, sum1 = 0.f;
        #pragma unroll
        for (int j = 0; j < 16; j++) {
            const float4 k4 = s_uk[pb][t3][j][p3];    // 4-dup broadcast
            const float4 v4 = s_uv[pb][t3][j][p3];
            const v2f ka = {k4.x, k4.y}, kb = {k4.z, k4.w};
            const v2f va = {v4.x, v4.y}, vb = {v4.z, v4.w};
            v2f t0 = uqa0 * ka;
            t0 += uqb0 * kb;
            const float e0 = EXP_FN(t0.x + t0.y);
            sum0 += e0;
            oa0 += va * e0;
            ob0 += vb * e0;
            v2f t1 = uqa1 * ka;
            t1 += uqb1 * kb;
            const float e1 = EXP_FN(t1.x + t1.y);
            sum1 += e1;
            oa1 += va * e1;
            ob1 += vb * e1;
        }
        v2f* __restrict__ out2 = (v2f*)out;
        {   const int i = ig * 2;
            const float rcp = RCP_FN(sum0);
            const v2f outa = oa0 * rcp + rsa0 * 0.125f;   // residual = mean/m
            const v2f outb = ob0 * rcp + rsb0 * 0.125f;
            const int obi = ((bb * 16 + i) * 64 + o) * 2048 + sp;
            out2[obi]      = outa;
            out2[obi + 32] = outb;
        }
        {   const int i = ig * 2 + 1;
            const float rcp = RCP_FN(sum1);
            const v2f outa = oa1 * rcp + rsa1 * 0.125f;
            const v2f outb = ob1 * rcp + rsb1 * 0.125f;
            const int obi = ((bb * 16 + i) * 64 + o) * 2048 + sp;
            out2[obi]      = outa;
            out2[obi + 32] = outb;
        }
    };

    // ---- W0: item0 q-conv + xk0 write ----
    v2f uqa0_0={0.f,0.f}, uqb0_0={0.f,0.f}, uqa1_0={0.f,0.f}, uqb1_0={0.f,0.f};
    v2f rsa0_0={0.f,0.f}, rsb0_0={0.f,0.f}, rsa1_0={0.f,0.f}, rsb1_0={0.f,0.f};
    const int sp0 = qconv(2 * u + 0, uqa0_0, uqb0_0, uqa1_0, uqb1_0,
                          rsa0_0, rsb0_0, rsa1_0, rsb1_0);
    *(float4*)&s_xk[0][st][sm][srow][sf * 2] = s1_0;
    __syncthreads();                       // BAR1: xk0 visible

    // ---- W1: stage2(item0) [LDS+VALU]  ||  q-loads+conv(item1) [VMEM+VALU] ----
    stage2(2 * u + 0, 0);
    v2f uqa0_1={0.f,0.f}, uqb0_1={0.f,0.f}, uqa1_1={0.f,0.f}, uqb1_1={0.f,0.f};
    v2f rsa0_1={0.f,0.f}, rsb0_1={0.f,0.f}, rsa1_1={0.f,0.f}, rsb1_1={0.f,0.f};
    const int sp1 = qconv(2 * u + 1, uqa0_1, uqb0_1, uqa1_1, uqb1_1,
                          rsa0_1, rsb0_1, rsa1_1, rsb1_1);
    *(float4*)&s_xk[1][st][sm][srow][sf * 2] = s1_1;
    __syncthreads();                       // BAR2: buf0 + xk1 visible

    // ---- W2: stage3(item0) [LDS+VALU+exp+stores] || stage2(item1) [LDS+VALU] ----
    stage3(0, sp0, uqa0_0, uqb0_0, uqa1_0, uqb1_0,
           rsa0_0, rsb0_0, rsa1_0, rsb1_0);
    stage2(2 * u + 1, 1);
    __syncthreads();                       // BAR3: buf1 visible

    // ---- W3: stage3(item1) ----
    stage3(1, sp1, uqa0_1, uqb0_1, uqa1_1, uqb1_1,
           rsa0_1, rsb0_1, rsa1_1, rsb1_1);
}

extern "C" void kernel_launch(void* const* d_in, const int* in_sizes, int n_in,
                              void* d_out, int out_size, void* d_ws, size_t ws_size,
                              hipStream_t stream) {
    const float* x  = (const float*)d_in[0];
    const float* wq = (const float*)d_in[1];
    const float* wk = (const float*)d_in[2];
    const float* wv = (const float*)d_in[3];
    const float* wp = (const float*)d_in[4];
    float* out = (float*)d_out;
    // 4 bb * 64 o * 16 u (2 tile-pair items each) = 4096 blocks of 256 threads
    adapt_attn<<<dim3(4096), dim3(256), 0, stream>>>(x, wq, wk, wv, wp, out);
}

// Round 10
// 119.255 us; speedup vs baseline: 1.0036x; 1.0005x over previous
//
#include <hip/hip_runtime.h>

typedef float v2f __attribute__((ext_vector_type(2)));

// ---- problem ----
// x:[4,16,8,64,64] f32, w_q/w_k/w_v:[64,8] f32, w_p:[2] f32
// out:[4,16,64,64,64] f32
// Attention batch B = bb*64 + o: q-side channel i (all 16) row o;
// k/v-side channel o>>2, w_k/w_v rows (o&3)*16+j; uk += 2*pe; scale 0.125
// folded into w_q (plus log2e when exp2 available); residual = mean over m;
// single-pass softmax (|logit| << 88): out = (sum_j e_j*uv_j)/(sum_j e_j).
//
// R20 = FINAL: restoration of R13, the best harness-verified kernel
// (118.24 us bench, ~53 us/dispatch, VGPR 56, no spill).
//
// Session findings (R10-R19), recorded for future work:
//  - dur x VALUBusy == ~26 us across ALL structures = the arithmetic floor
//    (~940M FMA + 67M exp at the 103 TF measured v_fma ceiling). The code
//    is at the instruction-count floor; the 2x residual is wave-level
//    stall no source-level structure reduced.
//  - Refuted hypotheses (each a controlled A/B): LDS bandwidth (R11),
//    occupancy (R11/R18: 25-56% occupancy, dur unchanged or worse),
//    VMEM-vs-LDS staging (R14: global-direct = 80 us, worse),
//    packed fp32 (R15: v_pk is no faster; asm chains block scheduling),
//    WG dispatch rate (R17), block granularity (R18), phase lockstep /
//    software pipelining (R19).
//  - RULE (2x confirmed): __launch_bounds__ min-waves must stay <= 4;
//    8 forces 32 VGPR -> ~850 MB scratch spill (R12, R16).
//  - Remaining lever: bf16-split MFMA for QK/AV (moves ~10 us of MACs to
//    the matrix pipe) — precision + layout risk, not attempted.

#if __has_builtin(__builtin_amdgcn_exp2f)
  #define EXP_FN(x) __builtin_amdgcn_exp2f(x)
  #define QSCALE 0.18033688011112043f   // 0.125 * log2(e)
#else
  #define EXP_FN(x) __expf(x)
  #define QSCALE 0.125f
#endif
#if __has_builtin(__builtin_amdgcn_rcpf)
  #define RCP_FN(x) __builtin_amdgcn_rcpf(x)
#else
  #define RCP_FN(x) (1.0f/(x))
#endif

__global__ __launch_bounds__(256, 4) void adapt_attn(
    const float* __restrict__ x,  const float* __restrict__ wq,
    const float* __restrict__ wk, const float* __restrict__ wv,
    const float* __restrict__ wp, float* __restrict__ out)
{
    __shared__ __align__(16) v2f s_xk[2][8][2][16];   // 4 KB  [t][m][row][p]
    __shared__ float4 s_uk[2][16][16];                // 8 KB  [t][j][p]
    __shared__ float4 s_uv[2][16][16];                // 8 KB   -> 20480 total

    const int tid = threadIdx.x;          // 0..255
    const int bid = blockIdx.x;           // ((bb*64+o)*32)+tg ; 8192 blocks
    const int tg = bid & 31;
    const int o  = (bid >> 5) & 63;
    const int bb = bid >> 11;
    const int r = o & 3, qch = o >> 2;

    const v2f*    __restrict__ x2 = (const v2f*)x;    // v2f strides: m 2048, row 32
    const float4* __restrict__ x4 = (const float4*)x; // f4 strides: m 1024, row 16

    // ---- A: issue stage-1 k/v staging load (1 float4 per thread) ----
    float4 s1;
    {
        const int f = tid & 7, row = (tid >> 3) & 1, m = (tid >> 4) & 7, t = tid >> 7;
        const int tile = tg * 2 + t;
        const int y0 = (tile >> 1) << 1, w8 = (tile & 1) * 8;
        s1 = x4[((bb * 16 + qch) * 8 + m) * 1024 + (y0 + row) * 16 + w8 + f];
    }

    // ---- C: q loads + q-conv + residual (hides A latency) ----
    const int p3 = tid & 15, ig = (tid >> 4) & 7, t3 = tid >> 7;
    const int tile3 = tg * 2 + t3;
    const int y03 = (tile3 >> 1) << 1, ww03 = (tile3 & 1) << 4;
    const int sp = y03 * 32 + ww03 + p3;  // v2f offset within a 64x64 plane

    float wqr[8];
    #pragma unroll
    for (int m = 0; m < 8; m++)
        wqr[m] = QSCALE * wq[(o << 3) + m];          // uniform scalar loads

    v2f qa0[8], qb0[8], qa1[8], qb1[8];
    {
        const int bq0 = (bb * 16 + ig * 2) * 16384 + sp;
        const int bq1 = bq0 + 16384;
        #pragma unroll
        for (int m = 0; m < 8; m++) {                // lanes 0-15 coalesced 128B
            qa0[m] = x2[bq0 + m * 2048];
            qb0[m] = x2[bq0 + m * 2048 + 32];
            qa1[m] = x2[bq1 + m * 2048];
            qb1[m] = x2[bq1 + m * 2048 + 32];
        }
    }

    v2f uqa0 = {0.f,0.f}, uqb0 = {0.f,0.f}, rsa0 = {0.f,0.f}, rsb0 = {0.f,0.f};
    v2f uqa1 = {0.f,0.f}, uqb1 = {0.f,0.f}, rsa1 = {0.f,0.f}, rsb1 = {0.f,0.f};
    #pragma unroll
    for (int m = 0; m < 8; m++) {
        uqa0 += qa0[m] * wqr[m];          // wq pre-scaled (incl. log2e)
        uqb0 += qb0[m] * wqr[m];
        rsa0 += qa0[m];
        rsb0 += qb0[m];
        uqa1 += qa1[m] * wqr[m];
        uqb1 += qb1[m] * wqr[m];
        rsa1 += qa1[m];
        rsb1 += qb1[m];
    }

    // ---- D: LDS store for stage-1 tile ----
    {
        const int f = tid & 7, row = (tid >> 3) & 1, m = (tid >> 4) & 7, t = tid >> 7;
        *(float4*)&s_xk[t][m][row][f * 2] = s1;
    }

    // ---- B: stage-2 weights straight from global (L1-resident, 2 KB) ----
    const int p2 = tid & 15, j2 = (tid >> 4) & 15;   // per-thread j, both tiles
    float wkj[8], wvj[8];
    {
        const float4* wk4 = (const float4*)wk;
        const float4* wv4 = (const float4*)wv;
        const int rb = (r * 16 + j2) * 2;
        *(float4*)&wkj[0] = wk4[rb];   *(float4*)&wkj[4] = wk4[rb + 1];
        *(float4*)&wvj[0] = wv4[rb];   *(float4*)&wvj[4] = wv4[rb + 1];
    }
    const float wp0 = wp[0], wp1 = wp[1];
    __syncthreads();

    // ---- stage 2: build uk/uv[t][j2][p2] for both tiles ----
    const float step = 2.0f / 63.0f;
    #pragma unroll
    for (int t = 0; t < 2; t++) {
        const int tile = tg * 2 + t;
        const int y0 = (tile >> 1) << 1, ww0 = (tile & 1) << 4;
        const int wwp = ww0 + p2;
        const float lx0 = -1.0f + step * (float)(wwp << 1);
        const float lx1 = lx0 + step;
        const float ly0 = -1.0f + step * (float)y0;
        const float ly1 = ly0 + step;
        v2f ka = { 2.0f * (wp0 * lx0 + wp1 * ly0), 2.0f * (wp0 * lx1 + wp1 * ly0) };
        v2f kb = { 2.0f * (wp0 * lx0 + wp1 * ly1), 2.0f * (wp0 * lx1 + wp1 * ly1) };
        v2f va = {0.f, 0.f}, vb = {0.f, 0.f};

        #pragma unroll
        for (int m = 0; m < 8; m++) {
            const v2f xa = s_xk[t][m][0][p2];
            const v2f xb = s_xk[t][m][1][p2];
            ka += xa * wkj[m]; kb += xb * wkj[m];
            va += xa * wvj[m]; vb += xb * wvj[m];
        }
        s_uk[t][j2][p2] = make_float4(ka.x, ka.y, kb.x, kb.y);
        s_uv[t][j2][p2] = make_float4(va.x, va.y, vb.x, vb.y);
    }
    __syncthreads();

    // ---- stage 3: fused att + softmax + AV ----
    {
        v2f oa0 = {0.f, 0.f}, ob0 = {0.f, 0.f};
        v2f oa1 = {0.f, 0.f}, ob1 = {0.f, 0.f};
        float sum0 = 0.f, sum1 = 0.f;

        #pragma unroll
        for (int j = 0; j < 16; j++) {
            const float4 k4 = s_uk[t3][j][p3];    // 4-dup broadcast: free
            const float4 v4 = s_uv[t3][j][p3];
            const v2f ka = {k4.x, k4.y}, kb = {k4.z, k4.w};
            const v2f va = {v4.x, v4.y}, vb = {v4.z, v4.w};

            v2f t0 = uqa0 * ka;
            t0 += uqb0 * kb;
            const float e0 = EXP_FN(t0.x + t0.y);
            sum0 += e0;
            oa0 += va * e0;
            ob0 += vb * e0;

            v2f t1 = uqa1 * ka;
            t1 += uqb1 * kb;
            const float e1 = EXP_FN(t1.x + t1.y);
            sum1 += e1;
            oa1 += va * e1;
            ob1 += vb * e1;
        }

        v2f* __restrict__ out2 = (v2f*)out;
        {
            const int i = ig * 2;
            const float rcp = RCP_FN(sum0);
            const v2f outa = oa0 * rcp + rsa0 * 0.125f;   // residual = mean/m
            const v2f outb = ob0 * rcp + rsb0 * 0.125f;
            const int obi = ((bb * 16 + i) * 64 + o) * 2048 + sp;
            out2[obi]      = outa;    // row y03
            out2[obi + 32] = outb;    // row y03+1
        }
        {
            const int i = ig * 2 + 1;
            const float rcp = RCP_FN(sum1);
            const v2f outa = oa1 * rcp + rsa1 * 0.125f;
            const v2f outb = ob1 * rcp + rsb1 * 0.125f;
            const int obi = ((bb * 16 + i) * 64 + o) * 2048 + sp;
            out2[obi]      = outa;
            out2[obi + 32] = outb;
        }
    }
}

extern "C" void kernel_launch(void* const* d_in, const int* in_sizes, int n_in,
                              void* d_out, int out_size, void* d_ws, size_t ws_size,
                              hipStream_t stream) {
    const float* x  = (const float*)d_in[0];
    const float* wq = (const float*)d_in[1];
    const float* wk = (const float*)d_in[2];
    const float* wv = (const float*)d_in[3];
    const float* wp = (const float*)d_in[4];
    float* out = (float*)d_out;
    // 4 bb * 64 o * 32 tile-pairs = 8192 blocks of 256 threads
    adapt_attn<<<dim3(8192), dim3(256), 0, stream>>>(x, wq, wk, wv, wp, out);
}